// Round 12
// baseline (308.975 us; speedup 1.0000x reference)
//
#include <hip/hip_runtime.h>
#include <hip/hip_bf16.h>
#include <stdint.h>

// B=2, T=2048, E=1024, H=16, D=64 ; M = B*T = 4096
// Inputs fp32, output fp32. bf16 MFMA 16x16x32, fp32 accumulate. Scale 1/32.
// R12 = R10 design with the Ps row-stride fix (40 -> 72 shorts; offsets reach 63).
// Attention: S^T/O^T orientation -> per-lane softmax (2 shuffles), packed b64
// P-relayout, no block barriers, K/V direct from global (XCD L2-resident),
// heavy-qb-first dispatch. ws: xb/Ob 8 + Vt 8 + WtQKV 6 + Wto 2 = 24 MB.

typedef __attribute__((ext_vector_type(8))) short short8;    // 8 bf16
typedef __attribute__((ext_vector_type(4))) short short4v;   // 4 bf16
typedef __attribute__((ext_vector_type(4))) float f32x4;

#define MFMA16(a, b, c) __builtin_amdgcn_mfma_f32_16x16x32_bf16((a), (b), (c), 0, 0, 0)

static __device__ __forceinline__ unsigned short f2bf(float f) {
    union { float f; unsigned int u; } v; v.f = f;
    unsigned int r = v.u + 0x7fffu + ((v.u >> 16) & 1u);   // RNE
    return (unsigned short)(r >> 16);
}
// async global->LDS, 16B per lane; LDS dest = wave-uniform base + lane*16
static __device__ __forceinline__ void gload16(const unsigned short* g,
                                               unsigned short* l) {
    __builtin_amdgcn_global_load_lds(
        (const __attribute__((address_space(1))) void*)g,
        (__attribute__((address_space(3))) void*)l, 16, 0, 0);
}

// ---------------------------------------------------------------- convert x -> bf16
__global__ __launch_bounds__(256) void k_convert_x(const float* __restrict__ x,
                                                   unsigned short* __restrict__ xb) {
    int i = blockIdx.x * 256 + threadIdx.x;        // 8 elements/thread
    const float4* p = (const float4*)(x + (size_t)i * 8);
    float4 a = p[0], b = p[1];
    short8 o;
    o[0] = (short)f2bf(a.x); o[1] = (short)f2bf(a.y);
    o[2] = (short)f2bf(a.z); o[3] = (short)f2bf(a.w);
    o[4] = (short)f2bf(b.x); o[5] = (short)f2bf(b.y);
    o[6] = (short)f2bf(b.z); o[7] = (short)f2bf(b.w);
    ((short8*)xb)[i] = o;
}

// ---------------- transpose+convert all 4 weights: W [K,N] fp32 -> Wt [N,K] bf16
__global__ __launch_bounds__(256) void k_transpose_w4(
        const float* __restrict__ W0, const float* __restrict__ W1,
        const float* __restrict__ W2, const float* __restrict__ W3,
        unsigned short* __restrict__ T0, unsigned short* __restrict__ T1,
        unsigned short* __restrict__ T2, unsigned short* __restrict__ T3) {
    const float* W = (blockIdx.z == 0) ? W0 : (blockIdx.z == 1) ? W1
                     : (blockIdx.z == 2) ? W2 : W3;
    unsigned short* Wt = (blockIdx.z == 0) ? T0 : (blockIdx.z == 1) ? T1
                         : (blockIdx.z == 2) ? T2 : T3;
    __shared__ float tw[64][68];
    const int k0 = blockIdx.x * 64, n0 = blockIdx.y * 64;
    const int tid = threadIdx.x;
#pragma unroll
    for (int r = 0; r < 4; ++r) {
        int i = tid + r * 256;
        int row = i >> 4, c4 = (i & 15) * 4;
        float4 v = *(const float4*)(W + (size_t)(k0 + row) * 1024 + n0 + c4);
        *(float4*)(&tw[row][c4]) = v;
    }
    __syncthreads();
#pragma unroll
    for (int r = 0; r < 2; ++r) {
        int i = tid + r * 256;
        int nrow = i >> 3, kc = (i & 7) * 8;
        short8 o;
#pragma unroll
        for (int j = 0; j < 8; ++j) o[j] = (short)f2bf(tw[kc + j][nrow]);
        *(short8*)(Wt + (size_t)(n0 + nrow) * 1024 + k0 + kc) = o;
    }
}

// ---------------------------------------------------------------- GEMM (m97 style)
// C[M=4096, N] = A[M,1024](bf16) @ Bt[N,1024]^T + bias ; 128x128 tile, BK=32.
// MODE 0 (QKV, N=3072): n0<1024 -> Qb ; <2048 -> Kb ; else V transposed into
// Vt[((b*16+h)*64+d)*2048+t]. MODE 1 (O, N=1024): fp32 out + bias.
template <int MODE>
__global__ __launch_bounds__(256) void k_gemm2(const unsigned short* __restrict__ A,
                                               const unsigned short* __restrict__ Bt,
                                               const float* __restrict__ bq,
                                               const float* __restrict__ bk,
                                               const float* __restrict__ bv,
                                               unsigned short* __restrict__ Qb,
                                               unsigned short* __restrict__ Kb,
                                               unsigned short* __restrict__ Vt,
                                               float* __restrict__ Co) {
    __shared__ unsigned short As[128 * 32];        // unpadded: global_load_lds dest
    __shared__ unsigned short Bs[128 * 32];
    const int tid = threadIdx.x;
    const int w = tid >> 6, lane = tid & 63;
    const int quad = lane >> 4, l16 = lane & 15;
    const int wm = w >> 1, wn = w & 1;             // 2x2 waves, 64x64 out each
    const int m0 = blockIdx.x * 128, n0 = blockIdx.y * 128;
    const int lrow = lane >> 2, lch = (lane & 3) * 8;

    const unsigned short* ga = A + (size_t)(m0 + w * 32 + lrow) * 1024 + lch;
    const unsigned short* gb = Bt + (size_t)(n0 + w * 32 + lrow) * 1024 + lch;
    unsigned short* la0 = &As[(w * 32) * 32];
    unsigned short* la1 = &As[(w * 32 + 16) * 32];
    unsigned short* lb0 = &Bs[(w * 32) * 32];
    unsigned short* lb1 = &Bs[(w * 32 + 16) * 32];

    f32x4 acc[4][4];
#pragma unroll
    for (int mt = 0; mt < 4; ++mt)
#pragma unroll
        for (int nt = 0; nt < 4; ++nt) acc[mt][nt] = (f32x4){0.f, 0.f, 0.f, 0.f};

    for (int k0 = 0; k0 < 1024; k0 += 32) {
        __syncthreads();                           // prev readers done
        gload16(ga + k0, la0);
        gload16(ga + 16 * 1024 + k0, la1);
        gload16(gb + k0, lb0);
        gload16(gb + 16 * 1024 + k0, lb1);
        __syncthreads();                           // vmcnt(0) drain + barrier
        short8 af[4], bf[4];
#pragma unroll
        for (int mt = 0; mt < 4; ++mt)
            af[mt] = *(const short8*)(&As[(wm * 64 + mt * 16 + l16) * 32 + quad * 8]);
#pragma unroll
        for (int nt = 0; nt < 4; ++nt)
            bf[nt] = *(const short8*)(&Bs[(wn * 64 + nt * 16 + l16) * 32 + quad * 8]);
#pragma unroll
        for (int mt = 0; mt < 4; ++mt)
#pragma unroll
            for (int nt = 0; nt < 4; ++nt)
                acc[mt][nt] = MFMA16(af[mt], bf[nt], acc[mt][nt]);
    }

    // epilogue: C/D layout col=lane&15, row=quad*4+reg
    if (MODE == 1) {
#pragma unroll
        for (int nt = 0; nt < 4; ++nt) {
            int col = n0 + wn * 64 + nt * 16 + l16;
            float bb = bq[col];
#pragma unroll
            for (int mt = 0; mt < 4; ++mt) {
                int row = m0 + wm * 64 + mt * 16 + quad * 4;
#pragma unroll
                for (int r = 0; r < 4; ++r)
                    Co[(size_t)(row + r) * 1024 + col] = acc[mt][nt][r] + bb;
            }
        }
    } else if (n0 < 2048) {                        // Q or K: bf16 row-major
        unsigned short* C = (n0 < 1024) ? Qb : Kb;
        const float* bias = (n0 < 1024) ? bq : bk;
        int cb = (n0 < 1024) ? n0 : (n0 - 1024);
#pragma unroll
        for (int nt = 0; nt < 4; ++nt) {
            int col = cb + wn * 64 + nt * 16 + l16;
            float bb = bias[col];
#pragma unroll
            for (int mt = 0; mt < 4; ++mt) {
                int row = m0 + wm * 64 + mt * 16 + quad * 4;
#pragma unroll
                for (int r = 0; r < 4; ++r)
                    C[(size_t)(row + r) * 1024 + col] = f2bf(acc[mt][nt][r] + bb);
            }
        }
    } else {                                       // V: transposed per-head store
#pragma unroll
        for (int nt = 0; nt < 4; ++nt) {
            int vcol = (n0 - 2048) + wn * 64 + nt * 16 + l16;   // h*64+d
            float bb = bv[vcol];
#pragma unroll
            for (int mt = 0; mt < 4; ++mt) {
                int row = m0 + wm * 64 + mt * 16 + quad * 4;    // b*2048+t, t%4==0
                int b = row >> 11, t = row & 2047;
                short4v o;
#pragma unroll
                for (int r = 0; r < 4; ++r) o[r] = (short)f2bf(acc[mt][nt][r] + bb);
                *(short4v*)(&Vt[((size_t)(b * 16 + (vcol >> 6)) * 64 + (vcol & 63))
                                    * 2048 + t]) = o;
            }
        }
    }
}

// ---------------------------------------------------------------- flash attention
// S^T/O^T orientation: softmax state per-lane (q = lane&15). No __syncthreads.
// grid 1024: bh = (id&7)+8*((id>>3)&3) (XCD-resident K/V), qb = 31-(id>>5)
// (heavy tiles dispatched first). Each wave owns 16 q rows.
__global__ __launch_bounds__(256) void k_attn(const unsigned short* __restrict__ Qb,
                                              const unsigned short* __restrict__ Kb,
                                              const unsigned short* __restrict__ Vt,
                                              unsigned short* __restrict__ Ob) {
    __shared__ unsigned short Ps[4][16][72];       // per-wave P^T; offsets reach 63,
                                                   // stride 72 (144B = 9*16B aligned)
    const int tid = threadIdx.x;
    const int w = tid >> 6, lane = tid & 63;
    const int quad = lane >> 4, l16 = lane & 15;
    const int id = blockIdx.x;
    const int bh = (id & 7) + 8 * ((id >> 3) & 3);
    const int qb = 31 - (id >> 5);
    const int b = bh >> 4, h = bh & 15;
    const float scale = 0.03125f;                  // 1/sqrt(1024)
    const int q0 = qb * 64 + w * 16;               // this wave's q base
    const int qg = q0 + l16;                       // this lane's q row
    const f32x4 zero4 = {0.f, 0.f, 0.f, 0.f};

    // Q as B-operand: [n=q=l16][k=d=quad*8+j], d-halves 0 and 32
    short8 qf[2];
    {
        const unsigned short* qp =
            Qb + (size_t)(b * 2048 + qg) * 1024 + h * 64 + quad * 8;
        qf[0] = *(const short8*)(qp);
        qf[1] = *(const short8*)(qp + 32);
    }
    float m_ = -1e30f, l_ = 0.f;                   // per lane (q), dup over quads
    f32x4 o[4];                                    // O^T: q=l16, d=dt*16+quad*4+r
#pragma unroll
    for (int dt = 0; dt < 4; ++dt) o[dt] = zero4;

    const unsigned short* kb0 = Kb + (size_t)(b * 2048) * 1024 + h * 64;
    const unsigned short* vb0 = Vt + (size_t)(bh * 64) * 2048;

    for (int kt = 0; kt <= qb; ++kt) {
        // S^T = K Q^T : A=K[m=k16=l16][d], B=Q[n=q]. C: col=q, row=k16.
        f32x4 s[4];
#pragma unroll
        for (int kkt = 0; kkt < 4; ++kkt) {
            const unsigned short* kp =
                kb0 + (size_t)(kt * 64 + kkt * 16 + l16) * 1024 + quad * 8;
            short8 kf0 = *(const short8*)(kp);
            short8 kf1 = *(const short8*)(kp + 32);
            s[kkt] = MFMA16(kf0, qf[0], zero4);
            s[kkt] = MFMA16(kf1, qf[1], s[kkt]);
        }

        // scale + causal mask + per-lane softmax (all 16 values share q=qg)
        float mx = -1e30f;
#pragma unroll
        for (int kkt = 0; kkt < 4; ++kkt) {
            int kg = kt * 64 + kkt * 16 + quad * 4;
#pragma unroll
            for (int r = 0; r < 4; ++r) {
                float v = s[kkt][r] * scale;
                v = (kt == qb && kg + r > qg) ? -1e30f : v;
                s[kkt][r] = v;
                mx = fmaxf(mx, v);
            }
        }
        mx = fmaxf(mx, __shfl_xor(mx, 16, 64));    // reduce over quad lanes
        mx = fmaxf(mx, __shfl_xor(mx, 32, 64));
        float mn = fmaxf(m_, mx);
        float al = __expf(m_ - mn);
        m_ = mn;
        float sum = 0.f;
#pragma unroll
        for (int kkt = 0; kkt < 4; ++kkt)
#pragma unroll
            for (int r = 0; r < 4; ++r) {
                float p = __expf(s[kkt][r] - m_);
                s[kkt][r] = p;
                sum += p;
            }
        sum += __shfl_xor(sum, 16, 64);
        sum += __shfl_xor(sum, 32, 64);
        l_ = l_ * al + sum;
#pragma unroll
        for (int dt = 0; dt < 4; ++dt)
#pragma unroll
            for (int r = 0; r < 4; ++r) o[dt][r] *= al;

        // P^T relayout: per lane 4 consecutive k at row q=l16 -> one b64/kkt
#pragma unroll
        for (int kkt = 0; kkt < 4; ++kkt) {
            short4v pk;
#pragma unroll
            for (int r = 0; r < 4; ++r) pk[r] = (short)f2bf(s[kkt][r]);
            *(short4v*)(&Ps[w][l16][kkt * 16 + quad * 4]) = pk;
        }
        __threadfence_block();                     // lgkmcnt drain (per-wave Ps)

        // O^T += V^T P^T : A=V^T[m=d16=l16][k], B=P^T[n=q=l16][k]
#pragma unroll
        for (int kks = 0; kks < 2; ++kks) {
            short8 pf = *(const short8*)(&Ps[w][l16][kks * 32 + quad * 8]);
#pragma unroll
            for (int dt = 0; dt < 4; ++dt) {
                short8 vf = *(const short8*)(
                    vb0 + (size_t)(dt * 16 + l16) * 2048 + kt * 64 + kks * 32 + quad * 8);
                o[dt] = MFMA16(vf, pf, o[dt]);
            }
        }
    }

    // epilogue: lane q=qg, d = dt*16+quad*4+r -> 4 consecutive d per b64 store
    float inv = 1.0f / l_;
    unsigned short* op = Ob + (size_t)(b * 2048 + qg) * 1024 + h * 64 + quad * 4;
#pragma unroll
    for (int dt = 0; dt < 4; ++dt) {
        short4v ov;
#pragma unroll
        for (int r = 0; r < 4; ++r) ov[r] = (short)f2bf(o[dt][r] * inv);
        *(short4v*)(op + dt * 16) = ov;
    }
}

// ---------------------------------------------------------------- launch
extern "C" void kernel_launch(void* const* d_in, const int* in_sizes, int n_in,
                              void* d_out, int out_size, void* d_ws, size_t ws_size,
                              hipStream_t stream) {
    const float* x  = (const float*)d_in[0];
    const float* Wq = (const float*)d_in[1];
    const float* bq = (const float*)d_in[2];
    const float* Wk = (const float*)d_in[3];
    const float* bk = (const float*)d_in[4];
    const float* Wv = (const float*)d_in[5];
    const float* bv = (const float*)d_in[6];
    const float* Wo = (const float*)d_in[7];
    const float* bo = (const float*)d_in[8];
    float* out = (float*)d_out;                    // fp32 output

    const size_t M4 = 4194304, M1 = 1048576;
    const size_t NEED = (M4 + M4 + 3 * M1 + M1) * 2;   // 24 MB
    if (ws_size < NEED) return;
    unsigned short* ws = (unsigned short*)d_ws;
    unsigned short* xb  = ws;                      // 8 MB (dead after QKV gemm)
    unsigned short* Ob  = ws;                      //   ... then Ob (attn output)
    unsigned short* Vt  = ws + M4;                 // 8 MB, [(b*16+h)*64+d][t]
    unsigned short* WtQ = ws + 2 * M4;             // 6 MB: Wq^T,Wk^T,Wv^T stacked
    unsigned short* Wto = WtQ + 3 * M1;            // 2 MB: Wo^T
    unsigned short* Qb  = (unsigned short*)d_out;  // 8 MB scratch in d_out
    unsigned short* Kb  = Qb + M4;                 // 8 MB scratch in d_out

    k_convert_x<<<2048, 256, 0, stream>>>(x, xb);
    k_transpose_w4<<<dim3(16, 16, 4), 256, 0, stream>>>(
        Wq, Wk, Wv, Wo, WtQ, WtQ + M1, WtQ + 2 * M1, Wto);
    k_gemm2<0><<<dim3(32, 24), 256, 0, stream>>>(xb, WtQ, bq, bk, bv,
                                                 Qb, Kb, Vt, nullptr);
    k_attn<<<1024, 256, 0, stream>>>(Qb, Kb, Vt, Ob);
    k_gemm2<1><<<dim3(32, 8), 256, 0, stream>>>(Ob, Wto, bo, nullptr, nullptr,
                                                nullptr, nullptr, nullptr, out);
}

// Round 13
// 208.879 us; speedup vs baseline: 1.4792x; 1.4792x over previous
//
#include <hip/hip_runtime.h>
#include <hip/hip_bf16.h>
#include <stdint.h>

// B=2, T=2048, E=1024, H=16, D=64 ; M = B*T = 4096
// Inputs fp32, output fp32. bf16 MFMA 16x16x32, fp32 accumulate. Scale 1/32.
// R13: R12's per-lane softmax (S^T/O^T) + R9's cooperative LDS K/V staging,
// now double-buffered with register prefetch (1 barrier/iter). XCD-grouped bh,
// heavy-qb-first. ws: xb/Ob 8 + Vt 8 + WtQKV 6 + Wto 2 = 24 MB.

typedef __attribute__((ext_vector_type(8))) short short8;    // 8 bf16
typedef __attribute__((ext_vector_type(4))) short short4v;   // 4 bf16
typedef __attribute__((ext_vector_type(4))) float f32x4;

#define MFMA16(a, b, c) __builtin_amdgcn_mfma_f32_16x16x32_bf16((a), (b), (c), 0, 0, 0)

static __device__ __forceinline__ unsigned short f2bf(float f) {
    union { float f; unsigned int u; } v; v.f = f;
    unsigned int r = v.u + 0x7fffu + ((v.u >> 16) & 1u);   // RNE
    return (unsigned short)(r >> 16);
}
// async global->LDS, 16B per lane; LDS dest = wave-uniform base + lane*16
static __device__ __forceinline__ void gload16(const unsigned short* g,
                                               unsigned short* l) {
    __builtin_amdgcn_global_load_lds(
        (const __attribute__((address_space(1))) void*)g,
        (__attribute__((address_space(3))) void*)l, 16, 0, 0);
}

// ---------------------------------------------------------------- convert x -> bf16
__global__ __launch_bounds__(256) void k_convert_x(const float* __restrict__ x,
                                                   unsigned short* __restrict__ xb) {
    int i = blockIdx.x * 256 + threadIdx.x;        // 8 elements/thread
    const float4* p = (const float4*)(x + (size_t)i * 8);
    float4 a = p[0], b = p[1];
    short8 o;
    o[0] = (short)f2bf(a.x); o[1] = (short)f2bf(a.y);
    o[2] = (short)f2bf(a.z); o[3] = (short)f2bf(a.w);
    o[4] = (short)f2bf(b.x); o[5] = (short)f2bf(b.y);
    o[6] = (short)f2bf(b.z); o[7] = (short)f2bf(b.w);
    ((short8*)xb)[i] = o;
}

// ---------------- transpose+convert all 4 weights: W [K,N] fp32 -> Wt [N,K] bf16
__global__ __launch_bounds__(256) void k_transpose_w4(
        const float* __restrict__ W0, const float* __restrict__ W1,
        const float* __restrict__ W2, const float* __restrict__ W3,
        unsigned short* __restrict__ T0, unsigned short* __restrict__ T1,
        unsigned short* __restrict__ T2, unsigned short* __restrict__ T3) {
    const float* W = (blockIdx.z == 0) ? W0 : (blockIdx.z == 1) ? W1
                     : (blockIdx.z == 2) ? W2 : W3;
    unsigned short* Wt = (blockIdx.z == 0) ? T0 : (blockIdx.z == 1) ? T1
                         : (blockIdx.z == 2) ? T2 : T3;
    __shared__ float tw[64][68];
    const int k0 = blockIdx.x * 64, n0 = blockIdx.y * 64;
    const int tid = threadIdx.x;
#pragma unroll
    for (int r = 0; r < 4; ++r) {
        int i = tid + r * 256;
        int row = i >> 4, c4 = (i & 15) * 4;
        float4 v = *(const float4*)(W + (size_t)(k0 + row) * 1024 + n0 + c4);
        *(float4*)(&tw[row][c4]) = v;
    }
    __syncthreads();
#pragma unroll
    for (int r = 0; r < 2; ++r) {
        int i = tid + r * 256;
        int nrow = i >> 3, kc = (i & 7) * 8;
        short8 o;
#pragma unroll
        for (int j = 0; j < 8; ++j) o[j] = (short)f2bf(tw[kc + j][nrow]);
        *(short8*)(Wt + (size_t)(n0 + nrow) * 1024 + k0 + kc) = o;
    }
}

// ---------------------------------------------------------------- GEMM (m97 style)
// C[M=4096, N] = A[M,1024](bf16) @ Bt[N,1024]^T + bias ; 128x128 tile, BK=32.
// MODE 0 (QKV, N=3072): n0<1024 -> Qb ; <2048 -> Kb ; else V transposed into
// Vt[((b*16+h)*64+d)*2048+t]. MODE 1 (O, N=1024): fp32 out + bias.
template <int MODE>
__global__ __launch_bounds__(256) void k_gemm2(const unsigned short* __restrict__ A,
                                               const unsigned short* __restrict__ Bt,
                                               const float* __restrict__ bq,
                                               const float* __restrict__ bk,
                                               const float* __restrict__ bv,
                                               unsigned short* __restrict__ Qb,
                                               unsigned short* __restrict__ Kb,
                                               unsigned short* __restrict__ Vt,
                                               float* __restrict__ Co) {
    __shared__ unsigned short As[128 * 32];        // unpadded: global_load_lds dest
    __shared__ unsigned short Bs[128 * 32];
    const int tid = threadIdx.x;
    const int w = tid >> 6, lane = tid & 63;
    const int quad = lane >> 4, l16 = lane & 15;
    const int wm = w >> 1, wn = w & 1;             // 2x2 waves, 64x64 out each
    const int m0 = blockIdx.x * 128, n0 = blockIdx.y * 128;
    const int lrow = lane >> 2, lch = (lane & 3) * 8;

    const unsigned short* ga = A + (size_t)(m0 + w * 32 + lrow) * 1024 + lch;
    const unsigned short* gb = Bt + (size_t)(n0 + w * 32 + lrow) * 1024 + lch;
    unsigned short* la0 = &As[(w * 32) * 32];
    unsigned short* la1 = &As[(w * 32 + 16) * 32];
    unsigned short* lb0 = &Bs[(w * 32) * 32];
    unsigned short* lb1 = &Bs[(w * 32 + 16) * 32];

    f32x4 acc[4][4];
#pragma unroll
    for (int mt = 0; mt < 4; ++mt)
#pragma unroll
        for (int nt = 0; nt < 4; ++nt) acc[mt][nt] = (f32x4){0.f, 0.f, 0.f, 0.f};

    for (int k0 = 0; k0 < 1024; k0 += 32) {
        __syncthreads();                           // prev readers done
        gload16(ga + k0, la0);
        gload16(ga + 16 * 1024 + k0, la1);
        gload16(gb + k0, lb0);
        gload16(gb + 16 * 1024 + k0, lb1);
        __syncthreads();                           // vmcnt(0) drain + barrier
        short8 af[4], bf[4];
#pragma unroll
        for (int mt = 0; mt < 4; ++mt)
            af[mt] = *(const short8*)(&As[(wm * 64 + mt * 16 + l16) * 32 + quad * 8]);
#pragma unroll
        for (int nt = 0; nt < 4; ++nt)
            bf[nt] = *(const short8*)(&Bs[(wn * 64 + nt * 16 + l16) * 32 + quad * 8]);
#pragma unroll
        for (int mt = 0; mt < 4; ++mt)
#pragma unroll
            for (int nt = 0; nt < 4; ++nt)
                acc[mt][nt] = MFMA16(af[mt], bf[nt], acc[mt][nt]);
    }

    // epilogue: C/D layout col=lane&15, row=quad*4+reg
    if (MODE == 1) {
#pragma unroll
        for (int nt = 0; nt < 4; ++nt) {
            int col = n0 + wn * 64 + nt * 16 + l16;
            float bb = bq[col];
#pragma unroll
            for (int mt = 0; mt < 4; ++mt) {
                int row = m0 + wm * 64 + mt * 16 + quad * 4;
#pragma unroll
                for (int r = 0; r < 4; ++r)
                    Co[(size_t)(row + r) * 1024 + col] = acc[mt][nt][r] + bb;
            }
        }
    } else if (n0 < 2048) {                        // Q or K: bf16 row-major
        unsigned short* C = (n0 < 1024) ? Qb : Kb;
        const float* bias = (n0 < 1024) ? bq : bk;
        int cb = (n0 < 1024) ? n0 : (n0 - 1024);
#pragma unroll
        for (int nt = 0; nt < 4; ++nt) {
            int col = cb + wn * 64 + nt * 16 + l16;
            float bb = bias[col];
#pragma unroll
            for (int mt = 0; mt < 4; ++mt) {
                int row = m0 + wm * 64 + mt * 16 + quad * 4;
#pragma unroll
                for (int r = 0; r < 4; ++r)
                    C[(size_t)(row + r) * 1024 + col] = f2bf(acc[mt][nt][r] + bb);
            }
        }
    } else {                                       // V: transposed per-head store
#pragma unroll
        for (int nt = 0; nt < 4; ++nt) {
            int vcol = (n0 - 2048) + wn * 64 + nt * 16 + l16;   // h*64+d
            float bb = bv[vcol];
#pragma unroll
            for (int mt = 0; mt < 4; ++mt) {
                int row = m0 + wm * 64 + mt * 16 + quad * 4;    // b*2048+t, t%4==0
                int b = row >> 11, t = row & 2047;
                short4v o;
#pragma unroll
                for (int r = 0; r < 4; ++r) o[r] = (short)f2bf(acc[mt][nt][r] + bb);
                *(short4v*)(&Vt[((size_t)(b * 16 + (vcol >> 6)) * 64 + (vcol & 63))
                                    * 2048 + t]) = o;
            }
        }
    }
}

// ---------------------------------------------------------------- flash attention
// Per-lane softmax (S^T/O^T, q = lane&15) + double-buffered cooperative LDS
// staging of K/V (one barrier per K-tile). grid 1024: bh=(id&7)+8*((id>>3)&3)
// (XCD-resident K/V), qb=31-(id>>5) (heavy first). Wave owns 16 q rows.
__global__ __launch_bounds__(256) void k_attn(const unsigned short* __restrict__ Qb,
                                              const unsigned short* __restrict__ Kb,
                                              const unsigned short* __restrict__ Vt,
                                              unsigned short* __restrict__ Ob) {
    __shared__ unsigned short Ks[2][64][72];       // [buf][k16][d], 144B row stride
    __shared__ unsigned short Vs[2][64][72];       // [buf][d][k]
    __shared__ unsigned short Ps[4][16][72];       // per-wave P^T relayout
    const int tid = threadIdx.x;
    const int w = tid >> 6, lane = tid & 63;
    const int quad = lane >> 4, l16 = lane & 15;
    const int id = blockIdx.x;
    const int bh = (id & 7) + 8 * ((id >> 3) & 3);
    const int qb = 31 - (id >> 5);
    const int b = bh >> 4, h = bh & 15;
    const float scale = 0.03125f;                  // 1/sqrt(1024)
    const int qg = qb * 64 + w * 16 + l16;         // this lane's q row
    const f32x4 zero4 = {0.f, 0.f, 0.f, 0.f};

    // staging geometry: 512 b128 chunks, thread covers rows tid>>3 and 32+(tid>>3)
    const int srow = tid >> 3, sc8 = (tid & 7) * 8;
    const unsigned short* kg0 = Kb + (size_t)(b * 2048) * 1024 + h * 64 + sc8;
    const unsigned short* vg0 = Vt + (size_t)(bh * 64 + srow) * 2048 + sc8;

    // Q as B-operand: [n=q=l16][k=d=quad*8+j], d-halves 0 and 32
    short8 qf[2];
    {
        const unsigned short* qp =
            Qb + (size_t)(b * 2048 + qg) * 1024 + h * 64 + quad * 8;
        qf[0] = *(const short8*)(qp);
        qf[1] = *(const short8*)(qp + 32);
    }
    float m_ = -1e30f, l_ = 0.f;                   // per lane (q), dup over quads
    f32x4 o[4];                                    // O^T: q=l16, d=dt*16+quad*4+r
#pragma unroll
    for (int dt = 0; dt < 4; ++dt) o[dt] = zero4;

    // prologue: stage tile 0
    short8 kr0, kr1, vr0, vr1;
    kr0 = *(const short8*)(kg0 + (size_t)(srow) * 1024);
    kr1 = *(const short8*)(kg0 + (size_t)(32 + srow) * 1024);
    vr0 = *(const short8*)(vg0);
    vr1 = *(const short8*)(vg0 + (size_t)32 * 2048);
    *(short8*)(&Ks[0][srow][sc8]) = kr0;
    *(short8*)(&Ks[0][32 + srow][sc8]) = kr1;
    *(short8*)(&Vs[0][srow][sc8]) = vr0;
    *(short8*)(&Vs[0][32 + srow][sc8]) = vr1;
    __syncthreads();

    for (int kt = 0; kt <= qb; ++kt) {
        const int cur = kt & 1;
        const bool more = kt < qb;
        if (more) {                                // prefetch tile kt+1 into regs
            const unsigned short* kg = kg0 + (size_t)((kt + 1) * 64) * 1024;
            kr0 = *(const short8*)(kg + (size_t)(srow) * 1024);
            kr1 = *(const short8*)(kg + (size_t)(32 + srow) * 1024);
            vr0 = *(const short8*)(vg0 + (kt + 1) * 64);
            vr1 = *(const short8*)(vg0 + (size_t)32 * 2048 + (kt + 1) * 64);
        }

        // S^T = K Q^T : A=K[m=k16=l16][d] from LDS, B=Q. C: col=q, row=k16.
        f32x4 s[4];
#pragma unroll
        for (int kkt = 0; kkt < 4; ++kkt) {
            short8 kf0 = *(const short8*)(&Ks[cur][kkt * 16 + l16][quad * 8]);
            short8 kf1 = *(const short8*)(&Ks[cur][kkt * 16 + l16][32 + quad * 8]);
            s[kkt] = MFMA16(kf0, qf[0], zero4);
            s[kkt] = MFMA16(kf1, qf[1], s[kkt]);
        }

        // scale + causal mask + per-lane softmax (all 16 values share q=qg)
        float mx = -1e30f;
#pragma unroll
        for (int kkt = 0; kkt < 4; ++kkt) {
            int kg_ = kt * 64 + kkt * 16 + quad * 4;
#pragma unroll
            for (int r = 0; r < 4; ++r) {
                float v = s[kkt][r] * scale;
                v = (kt == qb && kg_ + r > qg) ? -1e30f : v;
                s[kkt][r] = v;
                mx = fmaxf(mx, v);
            }
        }
        mx = fmaxf(mx, __shfl_xor(mx, 16, 64));    // reduce over quad lanes
        mx = fmaxf(mx, __shfl_xor(mx, 32, 64));
        float mn = fmaxf(m_, mx);
        float al = __expf(m_ - mn);
        m_ = mn;
        float sum = 0.f;
#pragma unroll
        for (int kkt = 0; kkt < 4; ++kkt)
#pragma unroll
            for (int r = 0; r < 4; ++r) {
                float p = __expf(s[kkt][r] - m_);
                s[kkt][r] = p;
                sum += p;
            }
        sum += __shfl_xor(sum, 16, 64);
        sum += __shfl_xor(sum, 32, 64);
        l_ = l_ * al + sum;
#pragma unroll
        for (int dt = 0; dt < 4; ++dt)
#pragma unroll
            for (int r = 0; r < 4; ++r) o[dt][r] *= al;

        // P^T relayout: per lane 4 consecutive k at row q=l16 -> one b64/kkt
#pragma unroll
        for (int kkt = 0; kkt < 4; ++kkt) {
            short4v pk;
#pragma unroll
            for (int r = 0; r < 4; ++r) pk[r] = (short)f2bf(s[kkt][r]);
            *(short4v*)(&Ps[w][l16][kkt * 16 + quad * 4]) = pk;
        }
        __threadfence_block();                     // lgkmcnt drain (per-wave Ps)

        // O^T += V^T P^T : A=V^T[m=d16=l16][k] from LDS, B=P^T[n=q=l16][k]
#pragma unroll
        for (int kks = 0; kks < 2; ++kks) {
            short8 pf = *(const short8*)(&Ps[w][l16][kks * 32 + quad * 8]);
#pragma unroll
            for (int dt = 0; dt < 4; ++dt) {
                short8 vf = *(const short8*)(
                    &Vs[cur][dt * 16 + l16][kks * 32 + quad * 8]);
                o[dt] = MFMA16(vf, pf, o[dt]);
            }
        }

        if (more) {                                // write prefetch to other buffer
            const int nxt = cur ^ 1;               // readers of `cur` done above;
            *(short8*)(&Ks[nxt][srow][sc8]) = kr0; // writes touch only `nxt`
            *(short8*)(&Ks[nxt][32 + srow][sc8]) = kr1;
            *(short8*)(&Vs[nxt][srow][sc8]) = vr0;
            *(short8*)(&Vs[nxt][32 + srow][sc8]) = vr1;
            __syncthreads();                       // one barrier per iteration
        }
    }

    // epilogue: lane q=qg, d = dt*16+quad*4+r -> 4 consecutive d per b64 store
    float inv = 1.0f / l_;
    unsigned short* op = Ob + (size_t)(b * 2048 + qg) * 1024 + h * 64 + quad * 4;
#pragma unroll
    for (int dt = 0; dt < 4; ++dt) {
        short4v ov;
#pragma unroll
        for (int r = 0; r < 4; ++r) ov[r] = (short)f2bf(o[dt][r] * inv);
        *(short4v*)(op + dt * 16) = ov;
    }
}

// ---------------------------------------------------------------- launch
extern "C" void kernel_launch(void* const* d_in, const int* in_sizes, int n_in,
                              void* d_out, int out_size, void* d_ws, size_t ws_size,
                              hipStream_t stream) {
    const float* x  = (const float*)d_in[0];
    const float* Wq = (const float*)d_in[1];
    const float* bq = (const float*)d_in[2];
    const float* Wk = (const float*)d_in[3];
    const float* bk = (const float*)d_in[4];
    const float* Wv = (const float*)d_in[5];
    const float* bv = (const float*)d_in[6];
    const float* Wo = (const float*)d_in[7];
    const float* bo = (const float*)d_in[8];
    float* out = (float*)d_out;                    // fp32 output

    const size_t M4 = 4194304, M1 = 1048576;
    const size_t NEED = (M4 + M4 + 3 * M1 + M1) * 2;   // 24 MB
    if (ws_size < NEED) return;
    unsigned short* ws = (unsigned short*)d_ws;
    unsigned short* xb  = ws;                      // 8 MB (dead after QKV gemm)
    unsigned short* Ob  = ws;                      //   ... then Ob (attn output)
    unsigned short* Vt  = ws + M4;                 // 8 MB, [(b*16+h)*64+d][t]
    unsigned short* WtQ = ws + 2 * M4;             // 6 MB: Wq^T,Wk^T,Wv^T stacked
    unsigned short* Wto = WtQ + 3 * M1;            // 2 MB: Wo^T
    unsigned short* Qb  = (unsigned short*)d_out;  // 8 MB scratch in d_out
    unsigned short* Kb  = Qb + M4;                 // 8 MB scratch in d_out

    k_convert_x<<<2048, 256, 0, stream>>>(x, xb);
    k_transpose_w4<<<dim3(16, 16, 4), 256, 0, stream>>>(
        Wq, Wk, Wv, Wo, WtQ, WtQ + M1, WtQ + 2 * M1, Wto);
    k_gemm2<0><<<dim3(32, 24), 256, 0, stream>>>(xb, WtQ, bq, bk, bv,
                                                 Qb, Kb, Vt, nullptr);
    k_attn<<<1024, 256, 0, stream>>>(Qb, Kb, Vt, Ob);
    k_gemm2<1><<<dim3(32, 8), 256, 0, stream>>>(Ob, Wto, bo, nullptr, nullptr,
                                                nullptr, nullptr, nullptr, out);
}

// Round 14
// 204.416 us; speedup vs baseline: 1.5115x; 1.0218x over previous
//
#include <hip/hip_runtime.h>
#include <hip/hip_bf16.h>
#include <stdint.h>

// B=2, T=2048, E=1024, H=16, D=64 ; M = B*T = 4096
// Inputs fp32, output fp32. bf16 MFMA 16x16x32, fp32 accumulate. Scale 1/32.
// R14: (1) Q pre-scaled by 1/32 in QKV epilogue; (2) causal mask behind
// wave-uniform kt==qb branch; (3) o-rescale skipped via __any when max
// unchanged; (4) both GEMMs double-buffered with register prefetch
// (1 barrier/iter). ws: xb/Ob 8 + Vt 8 + WtQKV 6 + Wto 2 = 24 MB.

typedef __attribute__((ext_vector_type(8))) short short8;    // 8 bf16
typedef __attribute__((ext_vector_type(4))) short short4v;   // 4 bf16
typedef __attribute__((ext_vector_type(4))) float f32x4;

#define MFMA16(a, b, c) __builtin_amdgcn_mfma_f32_16x16x32_bf16((a), (b), (c), 0, 0, 0)

static __device__ __forceinline__ unsigned short f2bf(float f) {
    union { float f; unsigned int u; } v; v.f = f;
    unsigned int r = v.u + 0x7fffu + ((v.u >> 16) & 1u);   // RNE
    return (unsigned short)(r >> 16);
}

// ---------------------------------------------------------------- convert x -> bf16
__global__ __launch_bounds__(256) void k_convert_x(const float* __restrict__ x,
                                                   unsigned short* __restrict__ xb) {
    int i = blockIdx.x * 256 + threadIdx.x;        // 8 elements/thread
    const float4* p = (const float4*)(x + (size_t)i * 8);
    float4 a = p[0], b = p[1];
    short8 o;
    o[0] = (short)f2bf(a.x); o[1] = (short)f2bf(a.y);
    o[2] = (short)f2bf(a.z); o[3] = (short)f2bf(a.w);
    o[4] = (short)f2bf(b.x); o[5] = (short)f2bf(b.y);
    o[6] = (short)f2bf(b.z); o[7] = (short)f2bf(b.w);
    ((short8*)xb)[i] = o;
}

// ---------------- transpose+convert all 4 weights: W [K,N] fp32 -> Wt [N,K] bf16
__global__ __launch_bounds__(256) void k_transpose_w4(
        const float* __restrict__ W0, const float* __restrict__ W1,
        const float* __restrict__ W2, const float* __restrict__ W3,
        unsigned short* __restrict__ T0, unsigned short* __restrict__ T1,
        unsigned short* __restrict__ T2, unsigned short* __restrict__ T3) {
    const float* W = (blockIdx.z == 0) ? W0 : (blockIdx.z == 1) ? W1
                     : (blockIdx.z == 2) ? W2 : W3;
    unsigned short* Wt = (blockIdx.z == 0) ? T0 : (blockIdx.z == 1) ? T1
                         : (blockIdx.z == 2) ? T2 : T3;
    __shared__ float tw[64][68];
    const int k0 = blockIdx.x * 64, n0 = blockIdx.y * 64;
    const int tid = threadIdx.x;
#pragma unroll
    for (int r = 0; r < 4; ++r) {
        int i = tid + r * 256;
        int row = i >> 4, c4 = (i & 15) * 4;
        float4 v = *(const float4*)(W + (size_t)(k0 + row) * 1024 + n0 + c4);
        *(float4*)(&tw[row][c4]) = v;
    }
    __syncthreads();
#pragma unroll
    for (int r = 0; r < 2; ++r) {
        int i = tid + r * 256;
        int nrow = i >> 3, kc = (i & 7) * 8;
        short8 o;
#pragma unroll
        for (int j = 0; j < 8; ++j) o[j] = (short)f2bf(tw[kc + j][nrow]);
        *(short8*)(Wt + (size_t)(n0 + nrow) * 1024 + k0 + kc) = o;
    }
}

// --------------------------------------- GEMM, dbuf + register prefetch
// C[M=4096, N] = A[M,1024](bf16) @ Bt[N,1024]^T + bias ; 128x128 tile, BK=32.
// MODE 0 (QKV, N=3072): n0<1024 -> Qb (PRE-SCALED by 1/32) ; <2048 -> Kb ;
// else V transposed into Vt. MODE 1 (O, N=1024): fp32 out + bias.
template <int MODE>
__global__ __launch_bounds__(256) void k_gemm2(const unsigned short* __restrict__ A,
                                               const unsigned short* __restrict__ Bt,
                                               const float* __restrict__ bq,
                                               const float* __restrict__ bk,
                                               const float* __restrict__ bv,
                                               unsigned short* __restrict__ Qb,
                                               unsigned short* __restrict__ Kb,
                                               unsigned short* __restrict__ Vt,
                                               float* __restrict__ Co) {
    __shared__ unsigned short As[2][128 * 32];     // 16 KB x2
    __shared__ unsigned short Bs[2][128 * 32];
    const int tid = threadIdx.x;
    const int w = tid >> 6, lane = tid & 63;
    const int quad = lane >> 4, l16 = lane & 15;
    const int wm = w >> 1, wn = w & 1;             // 2x2 waves, 64x64 out each
    const int m0 = blockIdx.x * 128, n0 = blockIdx.y * 128;
    const int lrow = lane >> 2, lch = (lane & 3) * 8;

    const unsigned short* ga = A + (size_t)(m0 + w * 32 + lrow) * 1024 + lch;
    const unsigned short* gb = Bt + (size_t)(n0 + w * 32 + lrow) * 1024 + lch;
    const int lofs = w * 1024 + lane * 8;          // == (w*32+lrow)*32 + lch

    f32x4 acc[4][4];
#pragma unroll
    for (int mt = 0; mt < 4; ++mt)
#pragma unroll
        for (int nt = 0; nt < 4; ++nt) acc[mt][nt] = (f32x4){0.f, 0.f, 0.f, 0.f};

    // prologue: stage K-tile 0
    short8 ar0 = *(const short8*)(ga);
    short8 ar1 = *(const short8*)(ga + 16 * 1024);
    short8 br0 = *(const short8*)(gb);
    short8 br1 = *(const short8*)(gb + 16 * 1024);
    *(short8*)(&As[0][lofs]) = ar0;
    *(short8*)(&As[0][lofs + 512]) = ar1;
    *(short8*)(&Bs[0][lofs]) = br0;
    *(short8*)(&Bs[0][lofs + 512]) = br1;
    __syncthreads();

    for (int k0 = 0; k0 < 1024; k0 += 32) {
        const int cur = (k0 >> 5) & 1;
        const bool more = (k0 + 32) < 1024;
        if (more) {                                // prefetch next tile to regs
            ar0 = *(const short8*)(ga + k0 + 32);
            ar1 = *(const short8*)(ga + 16 * 1024 + k0 + 32);
            br0 = *(const short8*)(gb + k0 + 32);
            br1 = *(const short8*)(gb + 16 * 1024 + k0 + 32);
        }
        short8 af[4], bf[4];
#pragma unroll
        for (int mt = 0; mt < 4; ++mt)
            af[mt] = *(const short8*)(&As[cur][(wm * 64 + mt * 16 + l16) * 32 + quad * 8]);
#pragma unroll
        for (int nt = 0; nt < 4; ++nt)
            bf[nt] = *(const short8*)(&Bs[cur][(wn * 64 + nt * 16 + l16) * 32 + quad * 8]);
#pragma unroll
        for (int mt = 0; mt < 4; ++mt)
#pragma unroll
            for (int nt = 0; nt < 4; ++nt)
                acc[mt][nt] = MFMA16(af[mt], bf[nt], acc[mt][nt]);
        if (more) {                                // write prefetch to other buffer
            const int nxt = cur ^ 1;
            *(short8*)(&As[nxt][lofs]) = ar0;
            *(short8*)(&As[nxt][lofs + 512]) = ar1;
            *(short8*)(&Bs[nxt][lofs]) = br0;
            *(short8*)(&Bs[nxt][lofs + 512]) = br1;
            __syncthreads();                       // one barrier per iteration
        }
    }

    // epilogue: C/D layout col=lane&15, row=quad*4+reg
    if (MODE == 1) {
#pragma unroll
        for (int nt = 0; nt < 4; ++nt) {
            int col = n0 + wn * 64 + nt * 16 + l16;
            float bb = bq[col];
#pragma unroll
            for (int mt = 0; mt < 4; ++mt) {
                int row = m0 + wm * 64 + mt * 16 + quad * 4;
#pragma unroll
                for (int r = 0; r < 4; ++r)
                    Co[(size_t)(row + r) * 1024 + col] = acc[mt][nt][r] + bb;
            }
        }
    } else if (n0 < 2048) {                        // Q (pre-scaled) or K: bf16
        unsigned short* C = (n0 < 1024) ? Qb : Kb;
        const float* bias = (n0 < 1024) ? bq : bk;
        const float sc = (n0 < 1024) ? 0.03125f : 1.0f;   // fold 1/sqrt(E) into Q
        int cb = (n0 < 1024) ? n0 : (n0 - 1024);
#pragma unroll
        for (int nt = 0; nt < 4; ++nt) {
            int col = cb + wn * 64 + nt * 16 + l16;
            float bb = bias[col];
#pragma unroll
            for (int mt = 0; mt < 4; ++mt) {
                int row = m0 + wm * 64 + mt * 16 + quad * 4;
#pragma unroll
                for (int r = 0; r < 4; ++r)
                    C[(size_t)(row + r) * 1024 + col] = f2bf((acc[mt][nt][r] + bb) * sc);
            }
        }
    } else {                                       // V: transposed per-head store
#pragma unroll
        for (int nt = 0; nt < 4; ++nt) {
            int vcol = (n0 - 2048) + wn * 64 + nt * 16 + l16;   // h*64+d
            float bb = bv[vcol];
#pragma unroll
            for (int mt = 0; mt < 4; ++mt) {
                int row = m0 + wm * 64 + mt * 16 + quad * 4;    // b*2048+t, t%4==0
                int b = row >> 11, t = row & 2047;
                short4v o;
#pragma unroll
                for (int r = 0; r < 4; ++r) o[r] = (short)f2bf(acc[mt][nt][r] + bb);
                *(short4v*)(&Vt[((size_t)(b * 16 + (vcol >> 6)) * 64 + (vcol & 63))
                                    * 2048 + t]) = o;
            }
        }
    }
}

// ---------------------------------------------------------------- flash attention
// Per-lane softmax (S^T/O^T, q = lane&15), double-buffered LDS K/V staging,
// Q pre-scaled, mask behind uniform kt==qb branch, conditional o-rescale.
// grid 1024: bh=(id&7)+8*((id>>3)&3) (XCD-resident K/V), qb=31-(id>>5).
__global__ __launch_bounds__(256) void k_attn(const unsigned short* __restrict__ Qb,
                                              const unsigned short* __restrict__ Kb,
                                              const unsigned short* __restrict__ Vt,
                                              unsigned short* __restrict__ Ob) {
    __shared__ unsigned short Ks[2][64][72];       // [buf][k16][d], 144B row stride
    __shared__ unsigned short Vs[2][64][72];       // [buf][d][k]
    __shared__ unsigned short Ps[4][16][72];       // per-wave P^T relayout
    const int tid = threadIdx.x;
    const int w = tid >> 6, lane = tid & 63;
    const int quad = lane >> 4, l16 = lane & 15;
    const int id = blockIdx.x;
    const int bh = (id & 7) + 8 * ((id >> 3) & 3);
    const int qb = 31 - (id >> 5);
    const int b = bh >> 4, h = bh & 15;
    const int qg = qb * 64 + w * 16 + l16;         // this lane's q row
    const f32x4 zero4 = {0.f, 0.f, 0.f, 0.f};

    // staging geometry: 512 b128 chunks, thread covers rows tid>>3 and 32+(tid>>3)
    const int srow = tid >> 3, sc8 = (tid & 7) * 8;
    const unsigned short* kg0 = Kb + (size_t)(b * 2048) * 1024 + h * 64 + sc8;
    const unsigned short* vg0 = Vt + (size_t)(bh * 64 + srow) * 2048 + sc8;

    // Q as B-operand (pre-scaled by 1/32): [n=q=l16][k=d=quad*8+j]
    short8 qf[2];
    {
        const unsigned short* qp =
            Qb + (size_t)(b * 2048 + qg) * 1024 + h * 64 + quad * 8;
        qf[0] = *(const short8*)(qp);
        qf[1] = *(const short8*)(qp + 32);
    }
    float m_ = -1e30f, l_ = 0.f;                   // per lane (q), dup over quads
    f32x4 o[4];                                    // O^T: q=l16, d=dt*16+quad*4+r
#pragma unroll
    for (int dt = 0; dt < 4; ++dt) o[dt] = zero4;

    // prologue: stage tile 0
    short8 kr0, kr1, vr0, vr1;
    kr0 = *(const short8*)(kg0 + (size_t)(srow) * 1024);
    kr1 = *(const short8*)(kg0 + (size_t)(32 + srow) * 1024);
    vr0 = *(const short8*)(vg0);
    vr1 = *(const short8*)(vg0 + (size_t)32 * 2048);
    *(short8*)(&Ks[0][srow][sc8]) = kr0;
    *(short8*)(&Ks[0][32 + srow][sc8]) = kr1;
    *(short8*)(&Vs[0][srow][sc8]) = vr0;
    *(short8*)(&Vs[0][32 + srow][sc8]) = vr1;
    __syncthreads();

    for (int kt = 0; kt <= qb; ++kt) {
        const int cur = kt & 1;
        const bool more = kt < qb;
        if (more) {                                // prefetch tile kt+1 into regs
            const unsigned short* kg = kg0 + (size_t)((kt + 1) * 64) * 1024;
            kr0 = *(const short8*)(kg + (size_t)(srow) * 1024);
            kr1 = *(const short8*)(kg + (size_t)(32 + srow) * 1024);
            vr0 = *(const short8*)(vg0 + (kt + 1) * 64);
            vr1 = *(const short8*)(vg0 + (size_t)32 * 2048 + (kt + 1) * 64);
        }

        // S^T = K Q^T : A=K[m=k16=l16][d] from LDS, B=Q. C: col=q, row=k16.
        f32x4 s[4];
#pragma unroll
        for (int kkt = 0; kkt < 4; ++kkt) {
            short8 kf0 = *(const short8*)(&Ks[cur][kkt * 16 + l16][quad * 8]);
            short8 kf1 = *(const short8*)(&Ks[cur][kkt * 16 + l16][32 + quad * 8]);
            s[kkt] = MFMA16(kf0, qf[0], zero4);
            s[kkt] = MFMA16(kf1, qf[1], s[kkt]);
        }

        // causal mask only on the diagonal tile (wave-uniform scalar branch)
        if (kt == qb) {
#pragma unroll
            for (int kkt = 0; kkt < 4; ++kkt) {
                int kg_ = qb * 64 + kkt * 16 + quad * 4;
#pragma unroll
                for (int r = 0; r < 4; ++r)
                    if (kg_ + r > qg) s[kkt][r] = -1e30f;
            }
        }
        // per-lane online softmax (all 16 values share q=qg)
        float mx = -1e30f;
#pragma unroll
        for (int kkt = 0; kkt < 4; ++kkt)
#pragma unroll
            for (int r = 0; r < 4; ++r) mx = fmaxf(mx, s[kkt][r]);
        mx = fmaxf(mx, __shfl_xor(mx, 16, 64));    // reduce over quad lanes
        mx = fmaxf(mx, __shfl_xor(mx, 32, 64));
        const float mold = m_;
        m_ = fmaxf(m_, mx);
        float sum = 0.f;
#pragma unroll
        for (int kkt = 0; kkt < 4; ++kkt)
#pragma unroll
            for (int r = 0; r < 4; ++r) {
                float p = __expf(s[kkt][r] - m_);
                s[kkt][r] = p;
                sum += p;
            }
        sum += __shfl_xor(sum, 16, 64);
        sum += __shfl_xor(sum, 32, 64);
        if (__any(m_ > mold)) {                    // rescale only if max moved
            float al = __expf(mold - m_);
            l_ = l_ * al + sum;
#pragma unroll
            for (int dt = 0; dt < 4; ++dt)
#pragma unroll
                for (int r = 0; r < 4; ++r) o[dt][r] *= al;
        } else {
            l_ += sum;
        }

        // P^T relayout: per lane 4 consecutive k at row q=l16 -> one b64/kkt
#pragma unroll
        for (int kkt = 0; kkt < 4; ++kkt) {
            short4v pk;
#pragma unroll
            for (int r = 0; r < 4; ++r) pk[r] = (short)f2bf(s[kkt][r]);
            *(short4v*)(&Ps[w][l16][kkt * 16 + quad * 4]) = pk;
        }
        __threadfence_block();                     // lgkmcnt drain (per-wave Ps)

        // O^T += V^T P^T : A=V^T[m=d16=l16][k] from LDS, B=P^T[n=q=l16][k]
#pragma unroll
        for (int kks = 0; kks < 2; ++kks) {
            short8 pf = *(const short8*)(&Ps[w][l16][kks * 32 + quad * 8]);
#pragma unroll
            for (int dt = 0; dt < 4; ++dt) {
                short8 vf = *(const short8*)(
                    &Vs[cur][dt * 16 + l16][kks * 32 + quad * 8]);
                o[dt] = MFMA16(vf, pf, o[dt]);
            }
        }

        if (more) {                                // write prefetch to other buffer
            const int nxt = cur ^ 1;
            *(short8*)(&Ks[nxt][srow][sc8]) = kr0;
            *(short8*)(&Ks[nxt][32 + srow][sc8]) = kr1;
            *(short8*)(&Vs[nxt][srow][sc8]) = vr0;
            *(short8*)(&Vs[nxt][32 + srow][sc8]) = vr1;
            __syncthreads();                       // one barrier per iteration
        }
    }

    // epilogue: lane q=qg, d = dt*16+quad*4+r -> 4 consecutive d per b64 store
    float inv = 1.0f / l_;
    unsigned short* op = Ob + (size_t)(b * 2048 + qg) * 1024 + h * 64 + quad * 4;
#pragma unroll
    for (int dt = 0; dt < 4; ++dt) {
        short4v ov;
#pragma unroll
        for (int r = 0; r < 4; ++r) ov[r] = (short)f2bf(o[dt][r] * inv);
        *(short4v*)(op + dt * 16) = ov;
    }
}

// ---------------------------------------------------------------- launch
extern "C" void kernel_launch(void* const* d_in, const int* in_sizes, int n_in,
                              void* d_out, int out_size, void* d_ws, size_t ws_size,
                              hipStream_t stream) {
    const float* x  = (const float*)d_in[0];
    const float* Wq = (const float*)d_in[1];
    const float* bq = (const float*)d_in[2];
    const float* Wk = (const float*)d_in[3];
    const float* bk = (const float*)d_in[4];
    const float* Wv = (const float*)d_in[5];
    const float* bv = (const float*)d_in[6];
    const float* Wo = (const float*)d_in[7];
    const float* bo = (const float*)d_in[8];
    float* out = (float*)d_out;                    // fp32 output

    const size_t M4 = 4194304, M1 = 1048576;
    const size_t NEED = (M4 + M4 + 3 * M1 + M1) * 2;   // 24 MB
    if (ws_size < NEED) return;
    unsigned short* ws = (unsigned short*)d_ws;
    unsigned short* xb  = ws;                      // 8 MB (dead after QKV gemm)
    unsigned short* Ob  = ws;                      //   ... then Ob (attn output)
    unsigned short* Vt  = ws + M4;                 // 8 MB, [(b*16+h)*64+d][t]
    unsigned short* WtQ = ws + 2 * M4;             // 6 MB: Wq^T,Wk^T,Wv^T stacked
    unsigned short* Wto = WtQ + 3 * M1;            // 2 MB: Wo^T
    unsigned short* Qb  = (unsigned short*)d_out;  // 8 MB scratch in d_out
    unsigned short* Kb  = Qb + M4;                 // 8 MB scratch in d_out

    k_convert_x<<<2048, 256, 0, stream>>>(x, xb);
    k_transpose_w4<<<dim3(16, 16, 4), 256, 0, stream>>>(
        Wq, Wk, Wv, Wo, WtQ, WtQ + M1, WtQ + 2 * M1, Wto);
    k_gemm2<0><<<dim3(32, 24), 256, 0, stream>>>(xb, WtQ, bq, bk, bv,
                                                 Qb, Kb, Vt, nullptr);
    k_attn<<<1024, 256, 0, stream>>>(Qb, Kb, Vt, Ob);
    k_gemm2<1><<<dim3(32, 8), 256, 0, stream>>>(Ob, Wto, bo, nullptr, nullptr,
                                                nullptr, nullptr, nullptr, out);
}